// Round 12
// baseline (345.338 us; speedup 1.0000x reference)
//
#include <hip/hip_runtime.h>
#include <hip/hip_bf16.h>

typedef __bf16 bf16x8 __attribute__((ext_vector_type(8)));
typedef __bf16 bf16x4 __attribute__((ext_vector_type(4)));
typedef float  f32x4  __attribute__((ext_vector_type(4)));

#define T_SEQ 2048
#define D_HEAD 64
#define BH_N 32
#define NT_TILES (T_SEQ / 64)        // 32
#define QT_N 16                      // 128 q-rows per block
#define IMG_BYTES 16384              // per-(bh,kt) tile image: 8KB K + 8KB V
#define SCALE_LOG2 0.18033688011112042f   // 0.125 * log2(e)

#define WS_IMG ((size_t)0)
#define WS_MB  ((size_t)16u << 20)

static __device__ __forceinline__ f32x4 mfma32(bf16x8 a, bf16x8 b, f32x4 c) {
    return __builtin_amdgcn_mfma_f32_16x16x32_bf16(a, b, c, 0, 0, 0);
}

static __device__ __forceinline__ float fast_exp2(float x) {
#if __has_builtin(__builtin_amdgcn_exp2f)
    return __builtin_amdgcn_exp2f(x);   // raw v_exp_f32; inputs bounded, no fixup needed
#else
    return exp2f(x);
#endif
}

static __device__ __forceinline__ int sext_bit(unsigned w, int idx) {
#if __has_builtin(__builtin_amdgcn_sbfe)
    return __builtin_amdgcn_sbfe((int)w, idx, 1);      // v_bfe_i32: 1 instr
#else
    return (int)(w << (31 - idx)) >> 31;
#endif
}

// async global->LDS, 16B per lane. LDS dest is wave-uniform base + lane*16 (HW rule);
// the swizzle lives in the GLOBAL image layout, LDS stays linear.
static __device__ __forceinline__ void gload16(const void* g, void* l, int lane) {
#if __has_builtin(__builtin_amdgcn_global_load_lds)
    (void)lane;
    __builtin_amdgcn_global_load_lds(
        (const __attribute__((address_space(1))) void*)g,
        (__attribute__((address_space(3))) void*)l, 16, 0, 0);
#else
    *((f32x4*)l + lane) = *(const f32x4*)g;
#endif
}

// ---------------- prepass: build per-tile LDS images ----------------
// Image for (bh,kt), 16KB:
//   K half (8KB): row kr (key 0..63) x 128B; 16B chunk m = K[key][d-chunk m^(kr&7)]
//   V half (8KB): row r  (d   0..63) x 128B; 16B chunk m: u=m^(r&7), kh=u&1, g=u>>1,
//       bytes0-7 = V[32kh+4g+{0..3}][d=r], bytes8-15 = V[32kh+16+4g+{0..3}][d=r]

__global__ __launch_bounds__(256) void prep_kv(const float* __restrict__ k,
                                               const float* __restrict__ v,
                                               char* __restrict__ img) {
    __shared__ __bf16 t[64][72];
    const int bh = blockIdx.y, tt = blockIdx.x, tid = threadIdx.x;
    char* ob = img + ((size_t)bh * NT_TILES + tt) * IMG_BYTES;
    {
        const int kr = tid >> 2, qd = tid & 3, ke = kr & 7;
        const size_t base = ((size_t)bh * T_SEQ + tt * 64 + kr) * D_HEAD + qd * 16;
        const float4 a0 = *(const float4*)(k + base);
        const float4 a1 = *(const float4*)(k + base + 4);
        const float4 a2 = *(const float4*)(k + base + 8);
        const float4 a3 = *(const float4*)(k + base + 12);
        bf16x8 w0, w1;
        w0[0]=(__bf16)a0.x; w0[1]=(__bf16)a0.y; w0[2]=(__bf16)a0.z; w0[3]=(__bf16)a0.w;
        w0[4]=(__bf16)a1.x; w0[5]=(__bf16)a1.y; w0[6]=(__bf16)a1.z; w0[7]=(__bf16)a1.w;
        w1[0]=(__bf16)a2.x; w1[1]=(__bf16)a2.y; w1[2]=(__bf16)a2.z; w1[3]=(__bf16)a2.w;
        w1[4]=(__bf16)a3.x; w1[5]=(__bf16)a3.y; w1[6]=(__bf16)a3.z; w1[7]=(__bf16)a3.w;
        *(bf16x8*)(ob + kr * 128 + (((2 * qd + 0) ^ ke) << 4)) = w0;
        *(bf16x8*)(ob + kr * 128 + (((2 * qd + 1) ^ ke) << 4)) = w1;
    }
    {
        const int tr = tid >> 4, c4 = (tid & 15) * 4;
        const float* src = v + ((size_t)bh * T_SEQ + tt * 64) * D_HEAD;
#pragma unroll
        for (int p = 0; p < 4; ++p) {
            const int row = p * 16 + tr;
            const float4 f = *(const float4*)(src + row * D_HEAD + c4);
            t[c4+0][row] = (__bf16)f.x; t[c4+1][row] = (__bf16)f.y;
            t[c4+2][row] = (__bf16)f.z; t[c4+3][row] = (__bf16)f.w;
        }
        __syncthreads();
        const int d = tid >> 2;
        char* vb = ob + 8192 + d * 128;
#pragma unroll
        for (int mi = 0; mi < 2; ++mi) {
            const int m  = (tid & 3) * 2 + mi;
            const int u  = m ^ (d & 7);
            const int k0 = (u & 1) * 32 + (u >> 1) * 4;
            const bf16x4 lo = *(const bf16x4*)&t[d][k0];
            const bf16x4 hi = *(const bf16x4*)&t[d][k0 + 16];
            *(bf16x8*)(vb + m * 16) = __builtin_shufflevector(lo, hi, 0,1,2,3,4,5,6,7);
        }
    }
}

// mask prepass: transposed + pre-inverted + kh-pre-split keep-bit words.
// nbt[(t*2 + kh)*2048 + row] = ~bits(mask[row][t*64 + kh*32 .. +31])
__global__ void mpack(const int* __restrict__ m, unsigned* __restrict__ nbt) {
    const int i = blockIdx.x * 256 + threadIdx.x;
    const unsigned long long b = __ballot(m[i] != 0);
    if ((threadIdx.x & 63) == 0) {
        const int wi  = i >> 6;          // word index = row*32 + t
        const int row = wi >> 5;
        const int t   = wi & 31;
        nbt[(size_t)(t * 2 + 0) * 2048 + row] = ~(unsigned)b;
        nbt[(size_t)(t * 2 + 1) * 2048 + row] = ~(unsigned)(b >> 32);
    }
}

// ---------------- main kernel ----------------
// attn19 = attn16's winning conditions (QTILE=128 traffic, multiple barrier domains,
// coalesced nbt masks) + attn18's halved-LDS compute body (4 qs-chains per wave, ka/vv
// shared across them). Block = 256 thr = 4 waves: qp = w&1 -> 64-q group, kh = w>>1 ->
// 32-key half. Grid 512 -> 4 blocks/CU (threads 4x256=1024, LDS 4x33,280=133K, VGPR
// ~104 <= 128 cap of launch_bounds(256,4)) = 16 waves/CU in FOUR independent barrier
// domains (2x attn16). Per block-tile: 32 b128 LDS reads (half of attn16), 1/4 the mask
// loads and loop bookkeeping, at unchanged image traffic. 2-buffer double-buffer loop
// (attn15's verified skeleton), staging 4KB/wave.

__global__ __launch_bounds__(256, 4) void attn19(
    const float* __restrict__ q, const char* __restrict__ img,
    const unsigned* __restrict__ nbt, float* __restrict__ out)
{
    // XCD swizzle: linear block id -> (bh, qt) s.t. XCD x hosts bh in [4x, 4x+4), all qt.
    const int l   = blockIdx.x;          // 0..511
    const int m_  = l >> 3;              // 0..63
    const int bh  = ((l & 7) << 2) | (m_ & 3);
    const int qt  = m_ >> 2;             // 0..15 (128 q rows each)

    const int tid = threadIdx.x, wave = tid >> 6, lane = tid & 63;
    const int g = lane >> 4, ln = lane & 15;
    const int qp = wave & 1, kh = wave >> 1;
    const int g4 = g * 4;

    __shared__ __align__(16) char smem[33280];
    float* Ep = (float*)smem;                // epilogue overlay: [2][64][64] f32 per pass
    float* Os = (float*)(smem + 32768);      // row sums [2][64] per pass

    const int qw = qt * 128 + qp * 64;

    // ---- Q B-frags (log2-scaled): lane holds Q[qw+qs*16+ln][kc*32+g*8+j]
    bf16x8 qf[4][2];
#pragma unroll
    for (int qs = 0; qs < 4; ++qs) {
        const float* qpt = q + ((size_t)bh * T_SEQ + qw + qs * 16 + ln) * D_HEAD + g * 8;
#pragma unroll
        for (int kc = 0; kc < 2; ++kc) {
            const float4 f0 = *(const float4*)(qpt + kc * 32);
            const float4 f1 = *(const float4*)(qpt + kc * 32 + 4);
            qf[qs][kc][0]=(__bf16)(f0.x*SCALE_LOG2); qf[qs][kc][1]=(__bf16)(f0.y*SCALE_LOG2);
            qf[qs][kc][2]=(__bf16)(f0.z*SCALE_LOG2); qf[qs][kc][3]=(__bf16)(f0.w*SCALE_LOG2);
            qf[qs][kc][4]=(__bf16)(f1.x*SCALE_LOG2); qf[qs][kc][5]=(__bf16)(f1.y*SCALE_LOG2);
            qf[qs][kc][6]=(__bf16)(f1.z*SCALE_LOG2); qf[qs][kc][7]=(__bf16)(f1.w*SCALE_LOG2);
        }
    }

    f32x4 o[4][4];
#pragma unroll
    for (int qs = 0; qs < 4; ++qs)
#pragma unroll
        for (int mt = 0; mt < 4; ++mt) o[qs][mt] = (f32x4){0.f, 0.f, 0.f, 0.f};
    f32x4 osum[4] = { (f32x4){0.f,0.f,0.f,0.f}, (f32x4){0.f,0.f,0.f,0.f},
                      (f32x4){0.f,0.f,0.f,0.f}, (f32x4){0.f,0.f,0.f,0.f} };
    const bf16x8 ones8 = { (__bf16)1.0f, (__bf16)1.0f, (__bf16)1.0f, (__bf16)1.0f,
                           (__bf16)1.0f, (__bf16)1.0f, (__bf16)1.0f, (__bf16)1.0f };
    const f32x4 z4 = (f32x4){0.f, 0.f, 0.f, 0.f};   // persistent MFMA C-init

    const char* ibase = img + (size_t)bh * (NT_TILES * (size_t)IMG_BYTES);
    const unsigned* nb_base = nbt + (size_t)kh * 2048 + qw;

    // ---- loop-invariant LDS read offsets (hoisted once)
    int koffs[2][2];
#pragma unroll
    for (int ntl = 0; ntl < 2; ++ntl) {
        const int row = (2 * kh + ntl) * 16 + ln;
        const int rb = row * 128 + ((g ^ (ln & 7)) << 4);
        koffs[ntl][0] = rb; koffs[ntl][1] = rb ^ 64;
    }
    int voffs[4];
#pragma unroll
    for (int mt = 0; mt < 4; ++mt)
        voffs[mt] = (mt * 16 + ln) * 128 + ((((g << 1) | kh) ^ (ln & 7)) << 4);

    char* buf0 = smem;
    char* buf1 = smem + 16384;

    auto stage = [&](int tile, char* dstbase) {   // 4 waves x 4KB
        const char* src = ibase + (size_t)tile * IMG_BYTES + wave * 4096 + lane * 16;
        char* dst = dstbase + wave * 4096;
        gload16(src, dst, lane);
        gload16(src + 1024, dst + 1024, lane);
        gload16(src + 2048, dst + 2048, lane);
        gload16(src + 3072, dst + 3072, lane);
    };

    auto compute_tile = [&](const char* KB, const unsigned* nw) {
        const char* VB = KB + 8192;
        unsigned nbs[4];
#pragma unroll
        for (int qs = 0; qs < 4; ++qs) nbs[qs] = nw[qs] >> g4;

        // batch the 4 K b128 reads up front (shared across all 4 qs chains)
        bf16x8 ka[2][2];
#pragma unroll
        for (int ntl = 0; ntl < 2; ++ntl) {
            ka[ntl][0] = *(const bf16x8*)(KB + koffs[ntl][0]);
            ka[ntl][1] = *(const bf16x8*)(KB + koffs[ntl][1]);
        }

        // ---- S^T = K.Q^T; exp2 + mask -> merged P frags; 4 independent qs chains
        bf16x8 pa8[4];
#pragma unroll
        for (int ntl = 0; ntl < 2; ++ntl) {
            f32x4 c[4];
            __builtin_amdgcn_s_setprio(1);
#pragma unroll
            for (int qs = 0; qs < 4; ++qs) {
                c[qs] = mfma32(ka[ntl][0], qf[qs][0], z4);
                c[qs] = mfma32(ka[ntl][1], qf[qs][1], c[qs]);
            }
            __builtin_amdgcn_s_setprio(0);
#pragma unroll
            for (int qs = 0; qs < 4; ++qs) {
#pragma unroll
                for (int r = 0; r < 4; ++r) {
                    const float e = fast_exp2(c[qs][r]);
                    const int keep = sext_bit(nbs[qs], ntl * 16 + r);
                    const float p = __builtin_bit_cast(float,
                        __builtin_bit_cast(unsigned, e) & (unsigned)keep);
                    pa8[qs][ntl * 4 + r] = (__bf16)p;
                }
            }
        }

        // ---- row-sum + PV: V frags shared across all 4 qs
        bf16x8 vv[4];
#pragma unroll
        for (int mt = 0; mt < 4; ++mt) vv[mt] = *(const bf16x8*)(VB + voffs[mt]);
        __builtin_amdgcn_s_setprio(1);
#pragma unroll
        for (int qs = 0; qs < 4; ++qs) osum[qs] = mfma32(pa8[qs], ones8, osum[qs]);
#pragma unroll
        for (int mt = 0; mt < 4; ++mt)
#pragma unroll
            for (int qs = 0; qs < 4; ++qs)
                o[qs][mt] = mfma32(pa8[qs], vv[mt], o[qs][mt]);
        __builtin_amdgcn_s_setprio(0);
    };

    // prologue: tile 0 -> buf0
    stage(0, buf0);
    unsigned mwA[4], mwB[4];
#pragma unroll
    for (int qs = 0; qs < 4; ++qs) mwA[qs] = nb_base[qs * 16 + ln];
    __syncthreads();

#pragma unroll 1
    for (int i = 0; i < NT_TILES / 2; ++i) {
        const int t = 2 * i;
        // half A: consume buf0 (tile t), prefetch tile t+1 -> buf1
        stage(t + 1, buf1);
        {
            const unsigned* p = nb_base + (size_t)(t + 1) * 4096;
#pragma unroll
            for (int qs = 0; qs < 4; ++qs) mwB[qs] = p[qs * 16 + ln];
        }
        compute_tile(buf0, mwA);
        __syncthreads();
        // half B: consume buf1 (tile t+1), prefetch tile t+2 -> buf0
        if (i < NT_TILES / 2 - 1) {
            stage(t + 2, buf0);
            const unsigned* p = nb_base + (size_t)(t + 2) * 4096;
#pragma unroll
            for (int qs = 0; qs < 4; ++qs) mwA[qs] = p[qs * 16 + ln];
        }
        compute_tile(buf1, mwB);
        __syncthreads();
    }

    // ---- epilogue: two 64-row passes (pass == qp); kh halves combined through LDS
#pragma unroll
    for (int pass = 0; pass < 2; ++pass) {
        if (qp == pass) {
#pragma unroll
            for (int qs = 0; qs < 4; ++qs) {
#pragma unroll
                for (int mt = 0; mt < 4; ++mt)
#pragma unroll
                    for (int r = 0; r < 4; ++r)
                        Ep[(size_t)kh * 4096 + (qs * 16 + g * 4 + r) * 64 + mt * 16 + ln] = o[qs][mt][r];
                if (ln == 0) {
#pragma unroll
                    for (int r = 0; r < 4; ++r)
                        Os[kh * 64 + qs * 16 + g * 4 + r] = osum[qs][r];
                }
            }
        }
        __syncthreads();
        // cooperative, coalesced output: 64 rows x 64 d fp32 (256 threads -> 4 quads each)
#pragma unroll
        for (int p2 = 0; p2 < 4; ++p2) {
            const int idx = p2 * 256 + tid;
            const int row = idx >> 4, c4 = (idx & 15) * 4;
            const float sl = Os[row] + Os[64 + row];
            const float inv = (sl > 0.f) ? (1.f / sl) : 0.f;
            const float4 a  = *(const float4*)(Ep + row * 64 + c4);
            const float4 b4 = *(const float4*)(Ep + 4096 + row * 64 + c4);
            const float4 st = { (a.x + b4.x) * inv, (a.y + b4.y) * inv,
                                (a.z + b4.z) * inv, (a.w + b4.w) * inv };
            *(float4*)(out + ((size_t)bh * T_SEQ + qt * 128 + pass * 64 + row) * D_HEAD + c4) = st;
        }
        if (pass == 0) __syncthreads();   // Ep/Os reused by pass 1
    }
}

extern "C" void kernel_launch(void* const* d_in, const int* in_sizes, int n_in,
                              void* d_out, int out_size, void* d_ws, size_t ws_size,
                              hipStream_t stream) {
    const float* q    = (const float*)d_in[0];
    const float* k    = (const float*)d_in[1];
    const float* v    = (const float*)d_in[2];
    const int*   mask = (const int*)d_in[3];
    float*       out  = (float*)d_out;

    char* img = (char*)d_ws + WS_IMG;
    unsigned* nbt = (unsigned*)((char*)d_ws + WS_MB);

    prep_kv<<<dim3(NT_TILES, BH_N), 256, 0, stream>>>(k, v, img);
    mpack<<<(T_SEQ * T_SEQ) / 256, 256, 0, stream>>>(mask, nbt);
    attn19<<<dim3(QT_N * BH_N), 256, 0, stream>>>(q, img, nbt, out);
}

// Round 13
// 157.763 us; speedup vs baseline: 2.1890x; 2.1890x over previous
//
#include <hip/hip_runtime.h>
#include <hip/hip_bf16.h>

typedef __bf16 bf16x8 __attribute__((ext_vector_type(8)));
typedef __bf16 bf16x4 __attribute__((ext_vector_type(4)));
typedef float  f32x4  __attribute__((ext_vector_type(4)));

#define T_SEQ 2048
#define D_HEAD 64
#define BH_N 32
#define NT_TILES (T_SEQ / 64)        // 32
#define QT_N 16                      // 128 q-rows per block
#define IMG_BYTES 16384              // per-(bh,kt) tile image: 8KB K + 8KB V
#define SCALE_LOG2 0.18033688011112042f   // 0.125 * log2(e)

#define WS_IMG ((size_t)0)
#define WS_MB  ((size_t)16u << 20)

static __device__ __forceinline__ f32x4 mfma32(bf16x8 a, bf16x8 b, f32x4 c) {
    return __builtin_amdgcn_mfma_f32_16x16x32_bf16(a, b, c, 0, 0, 0);
}

static __device__ __forceinline__ float fast_exp2(float x) {
#if __has_builtin(__builtin_amdgcn_exp2f)
    return __builtin_amdgcn_exp2f(x);   // raw v_exp_f32; inputs bounded, no fixup needed
#else
    return exp2f(x);
#endif
}

static __device__ __forceinline__ int sext_bit(unsigned w, int idx) {
#if __has_builtin(__builtin_amdgcn_sbfe)
    return __builtin_amdgcn_sbfe((int)w, idx, 1);      // v_bfe_i32: 1 instr
#else
    return (int)(w << (31 - idx)) >> 31;
#endif
}

// async global->LDS, 16B per lane. LDS dest is wave-uniform base + lane*16 (HW rule);
// the swizzle lives in the GLOBAL image layout, LDS stays linear.
static __device__ __forceinline__ void gload16(const void* g, void* l, int lane) {
#if __has_builtin(__builtin_amdgcn_global_load_lds)
    (void)lane;
    __builtin_amdgcn_global_load_lds(
        (const __attribute__((address_space(1))) void*)g,
        (__attribute__((address_space(3))) void*)l, 16, 0, 0);
#else
    *((f32x4*)l + lane) = *(const f32x4*)g;
#endif
}

// ---------------- prepass: build per-tile LDS images ----------------
// Image for (bh,kt), 16KB:
//   K half (8KB): row kr (key 0..63) x 128B; 16B chunk m = K[key][d-chunk m^(kr&7)]
//   V half (8KB): row r  (d   0..63) x 128B; 16B chunk m: u=m^(r&7), kh=u&1, g=u>>1,
//       bytes0-7 = V[32kh+4g+{0..3}][d=r], bytes8-15 = V[32kh+16+4g+{0..3}][d=r]

__global__ __launch_bounds__(256) void prep_kv(const float* __restrict__ k,
                                               const float* __restrict__ v,
                                               char* __restrict__ img) {
    __shared__ __bf16 t[64][72];
    const int bh = blockIdx.y, tt = blockIdx.x, tid = threadIdx.x;
    char* ob = img + ((size_t)bh * NT_TILES + tt) * IMG_BYTES;
    {
        const int kr = tid >> 2, qd = tid & 3, ke = kr & 7;
        const size_t base = ((size_t)bh * T_SEQ + tt * 64 + kr) * D_HEAD + qd * 16;
        const float4 a0 = *(const float4*)(k + base);
        const float4 a1 = *(const float4*)(k + base + 4);
        const float4 a2 = *(const float4*)(k + base + 8);
        const float4 a3 = *(const float4*)(k + base + 12);
        bf16x8 w0, w1;
        w0[0]=(__bf16)a0.x; w0[1]=(__bf16)a0.y; w0[2]=(__bf16)a0.z; w0[3]=(__bf16)a0.w;
        w0[4]=(__bf16)a1.x; w0[5]=(__bf16)a1.y; w0[6]=(__bf16)a1.z; w0[7]=(__bf16)a1.w;
        w1[0]=(__bf16)a2.x; w1[1]=(__bf16)a2.y; w1[2]=(__bf16)a2.z; w1[3]=(__bf16)a2.w;
        w1[4]=(__bf16)a3.x; w1[5]=(__bf16)a3.y; w1[6]=(__bf16)a3.z; w1[7]=(__bf16)a3.w;
        *(bf16x8*)(ob + kr * 128 + (((2 * qd + 0) ^ ke) << 4)) = w0;
        *(bf16x8*)(ob + kr * 128 + (((2 * qd + 1) ^ ke) << 4)) = w1;
    }
    {
        const int tr = tid >> 4, c4 = (tid & 15) * 4;
        const float* src = v + ((size_t)bh * T_SEQ + tt * 64) * D_HEAD;
#pragma unroll
        for (int p = 0; p < 4; ++p) {
            const int row = p * 16 + tr;
            const float4 f = *(const float4*)(src + row * D_HEAD + c4);
            t[c4+0][row] = (__bf16)f.x; t[c4+1][row] = (__bf16)f.y;
            t[c4+2][row] = (__bf16)f.z; t[c4+3][row] = (__bf16)f.w;
        }
        __syncthreads();
        const int d = tid >> 2;
        char* vb = ob + 8192 + d * 128;
#pragma unroll
        for (int mi = 0; mi < 2; ++mi) {
            const int m  = (tid & 3) * 2 + mi;
            const int u  = m ^ (d & 7);
            const int k0 = (u & 1) * 32 + (u >> 1) * 4;
            const bf16x4 lo = *(const bf16x4*)&t[d][k0];
            const bf16x4 hi = *(const bf16x4*)&t[d][k0 + 16];
            *(bf16x8*)(vb + m * 16) = __builtin_shufflevector(lo, hi, 0,1,2,3,4,5,6,7);
        }
    }
}

// mask prepass: transposed + pre-inverted + kh-pre-split keep-bit words.
// nbt[(t*2 + kh)*2048 + row] = ~bits(mask[row][t*64 + kh*32 .. +31])
__global__ void mpack(const int* __restrict__ m, unsigned* __restrict__ nbt) {
    const int i = blockIdx.x * 256 + threadIdx.x;
    const unsigned long long b = __ballot(m[i] != 0);
    if ((threadIdx.x & 63) == 0) {
        const int wi  = i >> 6;          // word index = row*32 + t
        const int row = wi >> 5;
        const int t   = wi & 31;
        nbt[(size_t)(t * 2 + 0) * 2048 + row] = ~(unsigned)b;
        nbt[(size_t)(t * 2 + 1) * 2048 + row] = ~(unsigned)(b >> 32);
    }
}

// ---------------- main kernel ----------------
// attn20 = the attn19 hypothesis (halved LDS reads via 4 qs-chains/wave) SPILL-PROOFED.
// attn19 failed on a register cliff (launch_bounds(256,4) -> 64-VGPR cap vs the ~104
// the 4-chain body needs -> 744MB scratch writes). attn20: 256 thr / 4 waves
// (qp = w&1 -> 64-q group with 4 chains, kh = w>>1 -> 32-key half), launch_bounds(256,2)
// -> 256-VGPR cap, zero spill risk. Skeleton = attn16's verified 4x16KB ring with
// barrier every 2 tiles (2-tile drift window, 2 blocks/CU = 2 independent domains).
// Per block-tile vs attn16: 32 b128 LDS reads (half), 1/4 mask loads + bookkeeping,
// same 256MB image traffic. Sanity gates on counters: WRITE_SIZE ~16MB, VGPR ~104-128.

__global__ __launch_bounds__(256, 2) void attn20(
    const float* __restrict__ q, const char* __restrict__ img,
    const unsigned* __restrict__ nbt, float* __restrict__ out)
{
    // XCD swizzle: linear block id -> (bh, qt) s.t. XCD x hosts bh in [4x, 4x+4), all qt.
    const int l   = blockIdx.x;          // 0..511
    const int m_  = l >> 3;              // 0..63
    const int bh  = ((l & 7) << 2) | (m_ & 3);
    const int qt  = m_ >> 2;             // 0..15 (128 q rows each)

    const int tid = threadIdx.x, wave = tid >> 6, lane = tid & 63;
    const int g = lane >> 4, ln = lane & 15;
    const int qp = wave & 1, kh = wave >> 1;
    const int g4 = g * 4;

    __shared__ __align__(16) char smem[66048];
    float* Ep = (float*)smem;                // epilogue overlay: [2][64][64] f32 (b0+b1)
    float* Os = (float*)(smem + 65536);      // row sums [2][64]

    const int qw = qt * 128 + qp * 64;

    // ---- Q B-frags (log2-scaled): lane holds Q[qw+qs*16+ln][kc*32+g*8+j]
    bf16x8 qf[4][2];
#pragma unroll
    for (int qs = 0; qs < 4; ++qs) {
        const float* qpt = q + ((size_t)bh * T_SEQ + qw + qs * 16 + ln) * D_HEAD + g * 8;
#pragma unroll
        for (int kc = 0; kc < 2; ++kc) {
            const float4 f0 = *(const float4*)(qpt + kc * 32);
            const float4 f1 = *(const float4*)(qpt + kc * 32 + 4);
            qf[qs][kc][0]=(__bf16)(f0.x*SCALE_LOG2); qf[qs][kc][1]=(__bf16)(f0.y*SCALE_LOG2);
            qf[qs][kc][2]=(__bf16)(f0.z*SCALE_LOG2); qf[qs][kc][3]=(__bf16)(f0.w*SCALE_LOG2);
            qf[qs][kc][4]=(__bf16)(f1.x*SCALE_LOG2); qf[qs][kc][5]=(__bf16)(f1.y*SCALE_LOG2);
            qf[qs][kc][6]=(__bf16)(f1.z*SCALE_LOG2); qf[qs][kc][7]=(__bf16)(f1.w*SCALE_LOG2);
        }
    }

    f32x4 o[4][4];
#pragma unroll
    for (int qs = 0; qs < 4; ++qs)
#pragma unroll
        for (int mt = 0; mt < 4; ++mt) o[qs][mt] = (f32x4){0.f, 0.f, 0.f, 0.f};
    f32x4 osum[4] = { (f32x4){0.f,0.f,0.f,0.f}, (f32x4){0.f,0.f,0.f,0.f},
                      (f32x4){0.f,0.f,0.f,0.f}, (f32x4){0.f,0.f,0.f,0.f} };
    const bf16x8 ones8 = { (__bf16)1.0f, (__bf16)1.0f, (__bf16)1.0f, (__bf16)1.0f,
                           (__bf16)1.0f, (__bf16)1.0f, (__bf16)1.0f, (__bf16)1.0f };
    const f32x4 z4 = (f32x4){0.f, 0.f, 0.f, 0.f};   // persistent MFMA C-init

    const char* ibase = img + (size_t)bh * (NT_TILES * (size_t)IMG_BYTES);
    const unsigned* nb_base = nbt + (size_t)kh * 2048 + qw;

    // ---- loop-invariant LDS read offsets (hoisted once)
    int koffs[2][2];
#pragma unroll
    for (int ntl = 0; ntl < 2; ++ntl) {
        const int row = (2 * kh + ntl) * 16 + ln;
        const int rb = row * 128 + ((g ^ (ln & 7)) << 4);
        koffs[ntl][0] = rb; koffs[ntl][1] = rb ^ 64;
    }
    int voffs[4];
#pragma unroll
    for (int mt = 0; mt < 4; ++mt)
        voffs[mt] = (mt * 16 + ln) * 128 + ((((g << 1) | kh) ^ (ln & 7)) << 4);

    char* const b0 = smem;
    char* const b1 = smem + 16384;
    char* const b2 = smem + 32768;
    char* const b3 = smem + 49152;

    auto stage = [&](int tile, char* dstbase) {   // 4 waves x 4KB
        const char* src = ibase + (size_t)tile * IMG_BYTES + wave * 4096 + lane * 16;
        char* dst = dstbase + wave * 4096;
        gload16(src, dst, lane);
        gload16(src + 1024, dst + 1024, lane);
        gload16(src + 2048, dst + 2048, lane);
        gload16(src + 3072, dst + 3072, lane);
    };

    auto compute_tile = [&](const char* KB, const unsigned* nw) {
        const char* VB = KB + 8192;
        unsigned nbs[4];
#pragma unroll
        for (int qs = 0; qs < 4; ++qs) nbs[qs] = nw[qs] >> g4;

        // batch the 4 K b128 reads up front (shared across all 4 qs chains)
        bf16x8 ka[2][2];
#pragma unroll
        for (int ntl = 0; ntl < 2; ++ntl) {
            ka[ntl][0] = *(const bf16x8*)(KB + koffs[ntl][0]);
            ka[ntl][1] = *(const bf16x8*)(KB + koffs[ntl][1]);
        }

        // ---- S^T = K.Q^T; exp2 + mask -> merged P frags; 4 independent qs chains
        bf16x8 pa8[4];
#pragma unroll
        for (int ntl = 0; ntl < 2; ++ntl) {
            f32x4 c[4];
            __builtin_amdgcn_s_setprio(1);
#pragma unroll
            for (int qs = 0; qs < 4; ++qs) {
                c[qs] = mfma32(ka[ntl][0], qf[qs][0], z4);
                c[qs] = mfma32(ka[ntl][1], qf[qs][1], c[qs]);
            }
            __builtin_amdgcn_s_setprio(0);
#pragma unroll
            for (int qs = 0; qs < 4; ++qs) {
#pragma unroll
                for (int r = 0; r < 4; ++r) {
                    const float e = fast_exp2(c[qs][r]);
                    const int keep = sext_bit(nbs[qs], ntl * 16 + r);
                    const float p = __builtin_bit_cast(float,
                        __builtin_bit_cast(unsigned, e) & (unsigned)keep);
                    pa8[qs][ntl * 4 + r] = (__bf16)p;
                }
            }
        }

        // ---- row-sum + PV: V frags shared across all 4 qs
        bf16x8 vv[4];
#pragma unroll
        for (int mt = 0; mt < 4; ++mt) vv[mt] = *(const bf16x8*)(VB + voffs[mt]);
        __builtin_amdgcn_s_setprio(1);
#pragma unroll
        for (int qs = 0; qs < 4; ++qs) osum[qs] = mfma32(pa8[qs], ones8, osum[qs]);
#pragma unroll
        for (int mt = 0; mt < 4; ++mt)
#pragma unroll
            for (int qs = 0; qs < 4; ++qs)
                o[qs][mt] = mfma32(pa8[qs], vv[mt], o[qs][mt]);
        __builtin_amdgcn_s_setprio(0);
    };

    unsigned mwA[4], mwB[4];

    // prologue: tiles 0,1 -> b0,b1; masks for tile 0
    stage(0, b0);
    stage(1, b1);
#pragma unroll
    for (int qs = 0; qs < 4; ++qs) mwA[qs] = nb_base[qs * 16 + ln];
    __syncthreads();

    // main: 7 groups x 4 tiles (t = 0..27), barrier every 2 tiles
#pragma unroll 1
    for (int i = 0; i < 7; ++i) {
        const int t = 4 * i;
        {   // slot t: read b0, stage t+2 -> b2
            stage(t + 2, b2);
            const unsigned* p = nb_base + (size_t)(t + 1) * 4096;
#pragma unroll
            for (int qs = 0; qs < 4; ++qs) mwB[qs] = p[qs * 16 + ln];
            compute_tile(b0, mwA);
        }
        {   // slot t+1: read b1, stage t+3 -> b3
            stage(t + 3, b3);
            const unsigned* p = nb_base + (size_t)(t + 2) * 4096;
#pragma unroll
            for (int qs = 0; qs < 4; ++qs) mwA[qs] = p[qs * 16 + ln];
            compute_tile(b1, mwB);
        }
        __syncthreads();
        {   // slot t+2: read b2, stage t+4 -> b0
            stage(t + 4, b0);
            const unsigned* p = nb_base + (size_t)(t + 3) * 4096;
#pragma unroll
            for (int qs = 0; qs < 4; ++qs) mwB[qs] = p[qs * 16 + ln];
            compute_tile(b2, mwA);
        }
        {   // slot t+3: read b3, stage t+5 -> b1
            stage(t + 5, b1);
            const unsigned* p = nb_base + (size_t)(t + 4) * 4096;
#pragma unroll
            for (int qs = 0; qs < 4; ++qs) mwA[qs] = p[qs * 16 + ln];
            compute_tile(b3, mwB);
        }
        __syncthreads();
    }

    // tail: tiles 28..31 (stages 30,31 only)
    {   // t=28: read b0, stage 30 -> b2
        stage(30, b2);
        const unsigned* p = nb_base + (size_t)29 * 4096;
#pragma unroll
        for (int qs = 0; qs < 4; ++qs) mwB[qs] = p[qs * 16 + ln];
        compute_tile(b0, mwA);
    }
    {   // t=29: read b1, stage 31 -> b3
        stage(31, b3);
        const unsigned* p = nb_base + (size_t)30 * 4096;
#pragma unroll
        for (int qs = 0; qs < 4; ++qs) mwA[qs] = p[qs * 16 + ln];
        compute_tile(b1, mwB);
    }
    __syncthreads();
    {   // t=30: read b2
        const unsigned* p = nb_base + (size_t)31 * 4096;
#pragma unroll
        for (int qs = 0; qs < 4; ++qs) mwB[qs] = p[qs * 16 + ln];
        compute_tile(b2, mwA);
    }
    {   // t=31: read b3
        compute_tile(b3, mwB);
    }

    // ---- epilogue: two 64-row passes (pass == qp); kh halves combined through LDS.
    // Ep overlays b0/b1; last b0/b1 reads completed before the final barrier above.
#pragma unroll
    for (int pass = 0; pass < 2; ++pass) {
        if (qp == pass) {
#pragma unroll
            for (int qs = 0; qs < 4; ++qs) {
#pragma unroll
                for (int mt = 0; mt < 4; ++mt)
#pragma unroll
                    for (int r = 0; r < 4; ++r)
                        Ep[(size_t)kh * 4096 + (qs * 16 + g * 4 + r) * 64 + mt * 16 + ln] = o[qs][mt][r];
                if (ln == 0) {
#pragma unroll
                    for (int r = 0; r < 4; ++r)
                        Os[kh * 64 + qs * 16 + g * 4 + r] = osum[qs][r];
                }
            }
        }
        __syncthreads();
        // cooperative, coalesced output: 64 rows x 64 d fp32 (256 threads -> 4 quads each)
#pragma unroll
        for (int p2 = 0; p2 < 4; ++p2) {
            const int idx = p2 * 256 + tid;
            const int row = idx >> 4, c4 = (idx & 15) * 4;
            const float sl = Os[row] + Os[64 + row];
            const float inv = (sl > 0.f) ? (1.f / sl) : 0.f;
            const float4 a  = *(const float4*)(Ep + row * 64 + c4);
            const float4 b4 = *(const float4*)(Ep + 4096 + row * 64 + c4);
            const float4 st = { (a.x + b4.x) * inv, (a.y + b4.y) * inv,
                                (a.z + b4.z) * inv, (a.w + b4.w) * inv };
            *(float4*)(out + ((size_t)bh * T_SEQ + qt * 128 + pass * 64 + row) * D_HEAD + c4) = st;
        }
        if (pass == 0) __syncthreads();   // Ep/Os reused by pass 1
    }
}

extern "C" void kernel_launch(void* const* d_in, const int* in_sizes, int n_in,
                              void* d_out, int out_size, void* d_ws, size_t ws_size,
                              hipStream_t stream) {
    const float* q    = (const float*)d_in[0];
    const float* k    = (const float*)d_in[1];
    const float* v    = (const float*)d_in[2];
    const int*   mask = (const int*)d_in[3];
    float*       out  = (float*)d_out;

    char* img = (char*)d_ws + WS_IMG;
    unsigned* nbt = (unsigned*)((char*)d_ws + WS_MB);

    prep_kv<<<dim3(NT_TILES, BH_N), 256, 0, stream>>>(k, v, img);
    mpack<<<(T_SEQ * T_SEQ) / 256, 256, 0, stream>>>(mask, nbt);
    attn20<<<dim3(QT_N * BH_N), 256, 0, stream>>>(q, img, nbt, out);
}

// Round 14
// 153.702 us; speedup vs baseline: 2.2468x; 1.0264x over previous
//
#include <hip/hip_runtime.h>
#include <hip/hip_bf16.h>

typedef __bf16 bf16x8 __attribute__((ext_vector_type(8)));
typedef __bf16 bf16x4 __attribute__((ext_vector_type(4)));
typedef float  f32x4  __attribute__((ext_vector_type(4)));

#define T_SEQ 2048
#define D_HEAD 64
#define BH_N 32
#define NT_TILES (T_SEQ / 64)        // 32
#define QT_N 16                      // 128 q-rows per block
#define IMG_BYTES 16384              // per-(bh,kt) tile image: 8KB K + 8KB V
#define SCALE_LOG2 0.18033688011112042f   // 0.125 * log2(e)

#define WS_IMG ((size_t)0)
#define WS_MB  ((size_t)16u << 20)

static __device__ __forceinline__ f32x4 mfma32(bf16x8 a, bf16x8 b, f32x4 c) {
    return __builtin_amdgcn_mfma_f32_16x16x32_bf16(a, b, c, 0, 0, 0);
}

static __device__ __forceinline__ float fast_exp2(float x) {
#if __has_builtin(__builtin_amdgcn_exp2f)
    return __builtin_amdgcn_exp2f(x);   // raw v_exp_f32; inputs bounded, no fixup needed
#else
    return exp2f(x);
#endif
}

static __device__ __forceinline__ int sext_bit(unsigned w, int idx) {
#if __has_builtin(__builtin_amdgcn_sbfe)
    return __builtin_amdgcn_sbfe((int)w, idx, 1);      // v_bfe_i32: 1 instr
#else
    return (int)(w << (31 - idx)) >> 31;
#endif
}

// async global->LDS, 16B per lane. LDS dest is wave-uniform base + lane*16 (HW rule);
// the swizzle lives in the GLOBAL image layout, LDS stays linear.
static __device__ __forceinline__ void gload16(const void* g, void* l, int lane) {
#if __has_builtin(__builtin_amdgcn_global_load_lds)
    (void)lane;
    __builtin_amdgcn_global_load_lds(
        (const __attribute__((address_space(1))) void*)g,
        (__attribute__((address_space(3))) void*)l, 16, 0, 0);
#else
    *((f32x4*)l + lane) = *(const f32x4*)g;
#endif
}

// ---------------- prepass: build per-tile LDS images ----------------
// Image for (bh,kt), 16KB:
//   K half (8KB): row kr (key 0..63) x 128B; 16B chunk m = K[key][d-chunk m^(kr&7)]
//   V half (8KB): row r  (d   0..63) x 128B; 16B chunk m: u=m^(r&7), kh=u&1, g=u>>1,
//       bytes0-7 = V[32kh+4g+{0..3}][d=r], bytes8-15 = V[32kh+16+4g+{0..3}][d=r]

__global__ __launch_bounds__(256) void prep_kv(const float* __restrict__ k,
                                               const float* __restrict__ v,
                                               char* __restrict__ img) {
    __shared__ __bf16 t[64][72];
    const int bh = blockIdx.y, tt = blockIdx.x, tid = threadIdx.x;
    char* ob = img + ((size_t)bh * NT_TILES + tt) * IMG_BYTES;
    {
        const int kr = tid >> 2, qd = tid & 3, ke = kr & 7;
        const size_t base = ((size_t)bh * T_SEQ + tt * 64 + kr) * D_HEAD + qd * 16;
        const float4 a0 = *(const float4*)(k + base);
        const float4 a1 = *(const float4*)(k + base + 4);
        const float4 a2 = *(const float4*)(k + base + 8);
        const float4 a3 = *(const float4*)(k + base + 12);
        bf16x8 w0, w1;
        w0[0]=(__bf16)a0.x; w0[1]=(__bf16)a0.y; w0[2]=(__bf16)a0.z; w0[3]=(__bf16)a0.w;
        w0[4]=(__bf16)a1.x; w0[5]=(__bf16)a1.y; w0[6]=(__bf16)a1.z; w0[7]=(__bf16)a1.w;
        w1[0]=(__bf16)a2.x; w1[1]=(__bf16)a2.y; w1[2]=(__bf16)a2.z; w1[3]=(__bf16)a2.w;
        w1[4]=(__bf16)a3.x; w1[5]=(__bf16)a3.y; w1[6]=(__bf16)a3.z; w1[7]=(__bf16)a3.w;
        *(bf16x8*)(ob + kr * 128 + (((2 * qd + 0) ^ ke) << 4)) = w0;
        *(bf16x8*)(ob + kr * 128 + (((2 * qd + 1) ^ ke) << 4)) = w1;
    }
    {
        const int tr = tid >> 4, c4 = (tid & 15) * 4;
        const float* src = v + ((size_t)bh * T_SEQ + tt * 64) * D_HEAD;
#pragma unroll
        for (int p = 0; p < 4; ++p) {
            const int row = p * 16 + tr;
            const float4 f = *(const float4*)(src + row * D_HEAD + c4);
            t[c4+0][row] = (__bf16)f.x; t[c4+1][row] = (__bf16)f.y;
            t[c4+2][row] = (__bf16)f.z; t[c4+3][row] = (__bf16)f.w;
        }
        __syncthreads();
        const int d = tid >> 2;
        char* vb = ob + 8192 + d * 128;
#pragma unroll
        for (int mi = 0; mi < 2; ++mi) {
            const int m  = (tid & 3) * 2 + mi;
            const int u  = m ^ (d & 7);
            const int k0 = (u & 1) * 32 + (u >> 1) * 4;
            const bf16x4 lo = *(const bf16x4*)&t[d][k0];
            const bf16x4 hi = *(const bf16x4*)&t[d][k0 + 16];
            *(bf16x8*)(vb + m * 16) = __builtin_shufflevector(lo, hi, 0,1,2,3,4,5,6,7);
        }
    }
}

// mask prepass: transposed + pre-inverted + kh-pre-split keep-bit words.
// nbt[(t*2 + kh)*2048 + row] = ~bits(mask[row][t*64 + kh*32 .. +31])
__global__ void mpack(const int* __restrict__ m, unsigned* __restrict__ nbt) {
    const int i = blockIdx.x * 256 + threadIdx.x;
    const unsigned long long b = __ballot(m[i] != 0);
    if ((threadIdx.x & 63) == 0) {
        const int wi  = i >> 6;          // word index = row*32 + t
        const int row = wi >> 5;
        const int t   = wi & 31;
        nbt[(size_t)(t * 2 + 0) * 2048 + row] = ~(unsigned)b;
        nbt[(size_t)(t * 2 + 1) * 2048 + row] = ~(unsigned)(b >> 32);
    }
}

// ---------------- main kernel ----------------
// attn16 (REVERT: best measured kernel of the session, 57.6us). QTILE=128, 512 thr,
// 8 waves (qp = w&3 -> 32-q group, kh = w>>2 -> 32-key half), grid 512 = 2 blocks/CU.
// 4x16KB LDS ring, barrier every 2 tiles (16 barriers, 2-tile drift window -> phase
// diversity between the two resident blocks). Coalesced pre-inverted kh-split nbt
// masks (1-cacheline loads). z4 C-init, sbfe keep-bit, hoisted LDS offsets, setprio
// around MFMA clusters. Session ledger: staging-VALU fix +4%, XCD locality +3%,
// hoisting +4%, mask gathers +6%, barrier halving +5%; occupancy/T15/QTILE-resizing/
// LDS-halving/ILP all tested null-to-negative. This is the structure's measured floor.

__global__ __launch_bounds__(512, 4) void attn16(
    const float* __restrict__ q, const char* __restrict__ img,
    const unsigned* __restrict__ nbt, float* __restrict__ out)
{
    // XCD swizzle: linear block id -> (bh, qt) s.t. XCD x hosts bh in [4x, 4x+4), all qt.
    const int l   = blockIdx.x;          // 0..511
    const int m_  = l >> 3;              // 0..63
    const int bh  = ((l & 7) << 2) | (m_ & 3);
    const int qt  = m_ >> 2;             // 0..15 (128 q rows each)

    const int tid = threadIdx.x, wave = tid >> 6, lane = tid & 63;
    const int g = lane >> 4, ln = lane & 15;
    const int qp = wave & 3, kh = wave >> 2;
    const int g4 = g * 4;

    __shared__ __align__(16) char smem[66048];
    float* Ep = (float*)smem;                // epilogue overlay: [2][64][64] f32 (b0+b1)
    float* Os = (float*)(smem + 65536);      // row sums [2][64]

    const int qw = qt * 128 + qp * 32;

    // ---- Q B-frags (log2-scaled): lane n=ln holds Q[qw+qs*16+ln][kc*32+g*8+j]
    bf16x8 qf[2][2];
#pragma unroll
    for (int qs = 0; qs < 2; ++qs) {
        const float* qpt = q + ((size_t)bh * T_SEQ + qw + qs * 16 + ln) * D_HEAD + g * 8;
#pragma unroll
        for (int kc = 0; kc < 2; ++kc) {
            const float4 f0 = *(const float4*)(qpt + kc * 32);
            const float4 f1 = *(const float4*)(qpt + kc * 32 + 4);
            qf[qs][kc][0]=(__bf16)(f0.x*SCALE_LOG2); qf[qs][kc][1]=(__bf16)(f0.y*SCALE_LOG2);
            qf[qs][kc][2]=(__bf16)(f0.z*SCALE_LOG2); qf[qs][kc][3]=(__bf16)(f0.w*SCALE_LOG2);
            qf[qs][kc][4]=(__bf16)(f1.x*SCALE_LOG2); qf[qs][kc][5]=(__bf16)(f1.y*SCALE_LOG2);
            qf[qs][kc][6]=(__bf16)(f1.z*SCALE_LOG2); qf[qs][kc][7]=(__bf16)(f1.w*SCALE_LOG2);
        }
    }

    f32x4 o[2][4];
#pragma unroll
    for (int qs = 0; qs < 2; ++qs)
#pragma unroll
        for (int mt = 0; mt < 4; ++mt) o[qs][mt] = (f32x4){0.f, 0.f, 0.f, 0.f};
    f32x4 osum[2] = { (f32x4){0.f,0.f,0.f,0.f}, (f32x4){0.f,0.f,0.f,0.f} };
    const bf16x8 ones8 = { (__bf16)1.0f, (__bf16)1.0f, (__bf16)1.0f, (__bf16)1.0f,
                           (__bf16)1.0f, (__bf16)1.0f, (__bf16)1.0f, (__bf16)1.0f };
    const f32x4 z4 = (f32x4){0.f, 0.f, 0.f, 0.f};   // persistent MFMA C-init

    const char* ibase = img + (size_t)bh * (NT_TILES * (size_t)IMG_BYTES);
    const unsigned* nb_base = nbt + (size_t)kh * 2048 + qw;

    // ---- loop-invariant LDS read offsets (hoisted once)
    int koffs[2][2];
#pragma unroll
    for (int ntl = 0; ntl < 2; ++ntl) {
        const int row = (2 * kh + ntl) * 16 + ln;
        const int rb = row * 128 + ((g ^ (ln & 7)) << 4);
        koffs[ntl][0] = rb; koffs[ntl][1] = rb ^ 64;
    }
    int voffs[4];
#pragma unroll
    for (int mt = 0; mt < 4; ++mt)
        voffs[mt] = (mt * 16 + ln) * 128 + ((((g << 1) | kh) ^ (ln & 7)) << 4);

    char* const b0 = smem;
    char* const b1 = smem + 16384;
    char* const b2 = smem + 32768;
    char* const b3 = smem + 49152;

    auto stage = [&](int tile, char* dstbase) {
        const char* src = ibase + (size_t)tile * IMG_BYTES + wave * 2048 + lane * 16;
        char* dst = dstbase + wave * 2048;
        gload16(src, dst, lane);
        gload16(src + 1024, dst + 1024, lane);
    };

    auto compute_tile = [&](const char* KB, unsigned nw0, unsigned nw1) {
        const char* VB = KB + 8192;
        const unsigned nbs0 = nw0 >> g4;
        const unsigned nbs1 = nw1 >> g4;

        // batch the 4 K b128 reads up front
        bf16x8 ka[2][2];
#pragma unroll
        for (int ntl = 0; ntl < 2; ++ntl) {
            ka[ntl][0] = *(const bf16x8*)(KB + koffs[ntl][0]);
            ka[ntl][1] = *(const bf16x8*)(KB + koffs[ntl][1]);
        }

        // ---- S^T = K.Q^T; exp2 + mask -> merged P frags (key perm: j<4 grp0, j>=4 grp1)
        bf16x8 pa8[2];
#pragma unroll
        for (int ntl = 0; ntl < 2; ++ntl) {
#pragma unroll
            for (int qs = 0; qs < 2; ++qs) {
                __builtin_amdgcn_s_setprio(1);
                f32x4 c = mfma32(ka[ntl][0], qf[qs][0], z4);
                c = mfma32(ka[ntl][1], qf[qs][1], c);
                __builtin_amdgcn_s_setprio(0);
                const unsigned nbs = qs ? nbs1 : nbs0;
#pragma unroll
                for (int r = 0; r < 4; ++r) {
                    const float e = fast_exp2(c[r]);
                    const int keep = sext_bit(nbs, ntl * 16 + r);
                    const float p = __builtin_bit_cast(float,
                        __builtin_bit_cast(unsigned, e) & (unsigned)keep);
                    pa8[qs][ntl * 4 + r] = (__bf16)p;
                }
            }
        }

        // ---- row-sum + PV, batched V reads then pure-MFMA cluster under setprio
        bf16x8 vv[4];
#pragma unroll
        for (int mt = 0; mt < 4; ++mt) vv[mt] = *(const bf16x8*)(VB + voffs[mt]);
        __builtin_amdgcn_s_setprio(1);
#pragma unroll
        for (int qs = 0; qs < 2; ++qs) osum[qs] = mfma32(pa8[qs], ones8, osum[qs]);
#pragma unroll
        for (int mt = 0; mt < 4; ++mt)
#pragma unroll
            for (int qs = 0; qs < 2; ++qs)
                o[qs][mt] = mfma32(pa8[qs], vv[mt], o[qs][mt]);
        __builtin_amdgcn_s_setprio(0);
    };

    unsigned mwA0, mwA1, mwB0, mwB1;

    // prologue: tiles 0,1 -> b0,b1; masks for tile 0
    stage(0, b0);
    stage(1, b1);
    mwA0 = nb_base[ln]; mwA1 = nb_base[16 + ln];
    __syncthreads();

    // main: 7 groups x 4 tiles (t = 0..27), barrier every 2 tiles
#pragma unroll 1
    for (int i = 0; i < 7; ++i) {
        const int t = 4 * i;
        {   // slot t: read b0, stage t+2 -> b2
            stage(t + 2, b2);
            const unsigned* p = nb_base + (size_t)(t + 1) * 4096;
            mwB0 = p[ln]; mwB1 = p[16 + ln];
            compute_tile(b0, mwA0, mwA1);
        }
        {   // slot t+1: read b1, stage t+3 -> b3
            stage(t + 3, b3);
            const unsigned* p = nb_base + (size_t)(t + 2) * 4096;
            mwA0 = p[ln]; mwA1 = p[16 + ln];
            compute_tile(b1, mwB0, mwB1);
        }
        __syncthreads();
        {   // slot t+2: read b2, stage t+4 -> b0
            stage(t + 4, b0);
            const unsigned* p = nb_base + (size_t)(t + 3) * 4096;
            mwB0 = p[ln]; mwB1 = p[16 + ln];
            compute_tile(b2, mwA0, mwA1);
        }
        {   // slot t+3: read b3, stage t+5 -> b1
            stage(t + 5, b1);
            const unsigned* p = nb_base + (size_t)(t + 4) * 4096;
            mwA0 = p[ln]; mwA1 = p[16 + ln];
            compute_tile(b3, mwB0, mwB1);
        }
        __syncthreads();
    }

    // tail: tiles 28..31 (stages 30,31 only)
    {   // t=28: read b0, stage 30 -> b2
        stage(30, b2);
        const unsigned* p = nb_base + (size_t)29 * 4096;
        mwB0 = p[ln]; mwB1 = p[16 + ln];
        compute_tile(b0, mwA0, mwA1);
    }
    {   // t=29: read b1, stage 31 -> b3
        stage(31, b3);
        const unsigned* p = nb_base + (size_t)30 * 4096;
        mwA0 = p[ln]; mwA1 = p[16 + ln];
        compute_tile(b1, mwB0, mwB1);
    }
    __syncthreads();
    {   // t=30: read b2
        const unsigned* p = nb_base + (size_t)31 * 4096;
        mwB0 = p[ln]; mwB1 = p[16 + ln];
        compute_tile(b2, mwA0, mwA1);
    }
    {   // t=31: read b3
        compute_tile(b3, mwB0, mwB1);
    }

    // ---- epilogue: two 64-row passes; kh halves combined through LDS.
    // Ep overlays b0/b1 only; all b0/b1 reads finished before the last barrier, and
    // concurrent b2/b3 readers are disjoint from the Ep region.
#pragma unroll
    for (int pass = 0; pass < 2; ++pass) {
        if ((qp >> 1) == pass) {
            const int qpl = qp & 1;
#pragma unroll
            for (int qs = 0; qs < 2; ++qs) {
#pragma unroll
                for (int mt = 0; mt < 4; ++mt)
#pragma unroll
                    for (int r = 0; r < 4; ++r)
                        Ep[(size_t)kh * 4096 + (qpl * 32 + qs * 16 + g * 4 + r) * 64 + mt * 16 + ln] = o[qs][mt][r];
                if (ln == 0) {
#pragma unroll
                    for (int r = 0; r < 4; ++r)
                        Os[kh * 64 + qpl * 32 + qs * 16 + g * 4 + r] = osum[qs][r];
                }
            }
        }
        __syncthreads();
        // cooperative, coalesced output: 64 rows x 64 d fp32 (512 threads -> 2 quads each)
#pragma unroll
        for (int p2 = 0; p2 < 2; ++p2) {
            const int idx = p2 * 512 + tid;
            const int row = idx >> 4, c4 = (idx & 15) * 4;
            const float sl = Os[row] + Os[64 + row];
            const float inv = (sl > 0.f) ? (1.f / sl) : 0.f;
            const float4 a  = *(const float4*)(Ep + row * 64 + c4);
            const float4 b4 = *(const float4*)(Ep + 4096 + row * 64 + c4);
            const float4 st = { (a.x + b4.x) * inv, (a.y + b4.y) * inv,
                                (a.z + b4.z) * inv, (a.w + b4.w) * inv };
            *(float4*)(out + ((size_t)bh * T_SEQ + qt * 128 + pass * 64 + row) * D_HEAD + c4) = st;
        }
        if (pass == 0) __syncthreads();   // Ep/Os reused by pass 1
    }
}

extern "C" void kernel_launch(void* const* d_in, const int* in_sizes, int n_in,
                              void* d_out, int out_size, void* d_ws, size_t ws_size,
                              hipStream_t stream) {
    const float* q    = (const float*)d_in[0];
    const float* k    = (const float*)d_in[1];
    const float* v    = (const float*)d_in[2];
    const int*   mask = (const int*)d_in[3];
    float*       out  = (float*)d_out;

    char* img = (char*)d_ws + WS_IMG;
    unsigned* nbt = (unsigned*)((char*)d_ws + WS_MB);

    prep_kv<<<dim3(NT_TILES, BH_N), 256, 0, stream>>>(k, v, img);
    mpack<<<(T_SEQ * T_SEQ) / 256, 256, 0, stream>>>(mask, nbt);
    attn16<<<dim3(QT_N * BH_N), 512, 0, stream>>>(q, img, nbt, out);
}